// Round 7
// baseline (313.054 us; speedup 1.0000x reference)
//
#include <hip/hip_runtime.h>
#include <math.h>

#define D 128
#define CHUNK 1024
#define NPART 8   // dst-range partitions == XCD count; blockIdx%8 -> XCD round-robin
#define ST 64     // hz supertile rows
#define BK_T 256
#define BK_E 4    // edges per thread per bucket iteration

typedef short bf16x8 __attribute__((ext_vector_type(8)));
typedef short bf16x4 __attribute__((ext_vector_type(4)));
typedef float f32x4 __attribute__((ext_vector_type(4)));

__device__ inline unsigned short f2bf(float f) {
    union { float f; unsigned u; } v; v.f = f;
    unsigned r = v.u + 0x7fff + ((v.u >> 16) & 1);   // RNE
    return (unsigned short)(r >> 16);
}
__device__ inline float bf2f(unsigned short u) {
    union { unsigned u; float f; } v; v.u = ((unsigned)u) << 16;
    return v.f;
}

// ---------- CSR build ----------
__global__ __launch_bounds__(256) void hist_kernel(
    const int* __restrict__ edst, int* __restrict__ deg, int E)
{
    for (int e = blockIdx.x * blockDim.x + threadIdx.x; e < E;
         e += gridDim.x * blockDim.x)
        atomicAdd(&deg[edst[e]], 1);
}

__global__ __launch_bounds__(256) void chunksum_kernel(
    const int* __restrict__ deg, int* __restrict__ chunksum, int n)
{
    __shared__ int sc[256];
    int base = blockIdx.x * CHUNK;
    int t = threadIdx.x;
    int s = 0;
    for (int i = t; i < CHUNK; i += 256) {
        int idx = base + i;
        if (idx < n) s += deg[idx];
    }
    sc[t] = s;
    __syncthreads();
    for (int off = 128; off > 0; off >>= 1) {
        if (t < off) sc[t] += sc[t + off];
        __syncthreads();
    }
    if (t == 0) chunksum[blockIdx.x] = sc[0];
}

__global__ __launch_bounds__(128) void scanchunks_kernel(
    int* __restrict__ chunksum, int* __restrict__ offs, int nchunks, int n, int E)
{
    __shared__ int sc[128];
    int t = threadIdx.x;
    int v = (t < nchunks) ? chunksum[t] : 0;
    sc[t] = v;
    __syncthreads();
    for (int off = 1; off < 128; off <<= 1) {
        int add = (t >= off) ? sc[t - off] : 0;
        __syncthreads();
        sc[t] += add;
        __syncthreads();
    }
    if (t < nchunks) chunksum[t] = sc[t] - v;   // exclusive
    if (t == 0) offs[n] = E;
}

__global__ __launch_bounds__(256) void offsets_kernel(
    const int* __restrict__ deg, const int* __restrict__ chunksum,
    int* __restrict__ offs, int* __restrict__ cursor, int n)
{
    __shared__ int sc[256];
    int base = blockIdx.x * CHUNK;
    int t = threadIdx.x;
    int idx0 = base + t * 4;
    int d0 = 0, d1 = 0, d2 = 0, d3 = 0;
    if (idx0 + 0 < n) d0 = deg[idx0 + 0];
    if (idx0 + 1 < n) d1 = deg[idx0 + 1];
    if (idx0 + 2 < n) d2 = deg[idx0 + 2];
    if (idx0 + 3 < n) d3 = deg[idx0 + 3];
    int mysum = d0 + d1 + d2 + d3;
    sc[t] = mysum;
    __syncthreads();
    for (int off = 1; off < 256; off <<= 1) {
        int add = (t >= off) ? sc[t - off] : 0;
        __syncthreads();
        sc[t] += add;
        __syncthreads();
    }
    int prefix = chunksum[blockIdx.x] + sc[t] - mysum;
    if (idx0 + 0 < n) { offs[idx0 + 0] = prefix; cursor[idx0 + 0] = prefix; prefix += d0; }
    if (idx0 + 1 < n) { offs[idx0 + 1] = prefix; cursor[idx0 + 1] = prefix; prefix += d1; }
    if (idx0 + 2 < n) { offs[idx0 + 2] = prefix; cursor[idx0 + 2] = prefix; prefix += d2; }
    if (idx0 + 3 < n) { offs[idx0 + 3] = prefix; cursor[idx0 + 3] = prefix; prefix += d3; }
}

__global__ void init_bcur_kernel(const int* __restrict__ offs,
                                 int* __restrict__ bcur, int ngene)
{
    int p = threadIdx.x;
    if (p < NPART) bcur[p] = offs[(int)((long long)p * ngene / NPART)];
}

// ---------- bucket: one sweep packs (dst,src) into 8 dst-range buckets (dense writes) ----
__global__ __launch_bounds__(256) void bucket_kernel(
    const int* __restrict__ esrc, const int* __restrict__ edst,
    int* __restrict__ bcur, unsigned long long* __restrict__ pairs,
    int E, int ngene)
{
    __shared__ int lcount[NPART];
    __shared__ int lbase[NPART];
    int t = threadIdx.x;
    const int batch = BK_T * BK_E;   // 1024 edges per block-iteration
    for (long long base = (long long)blockIdx.x * batch; base < E;
         base += (long long)gridDim.x * batch) {
        if (t < NPART) lcount[t] = 0;
        __syncthreads();
        int pp[BK_E], rr[BK_E], dd[BK_E], ss[BK_E];
        #pragma unroll
        for (int j = 0; j < BK_E; ++j) {
            int e = (int)base + t + j * BK_T;   // coalesced per sub-batch
            pp[j] = -1;
            if (e < E) {
                dd[j] = __builtin_nontemporal_load(&edst[e]);
                ss[j] = __builtin_nontemporal_load(&esrc[e]);
                int p = (int)(((long long)dd[j] * NPART) / ngene);
                while ((long long)p * ngene / NPART > dd[j]) --p;
                while ((long long)(p + 1) * ngene / NPART <= dd[j]) ++p;
                pp[j] = p;
                rr[j] = atomicAdd(&lcount[p], 1);
            }
        }
        __syncthreads();
        if (t < NPART) lbase[t] = lcount[t] ? atomicAdd(&bcur[t], lcount[t]) : 0;
        __syncthreads();
        #pragma unroll
        for (int j = 0; j < BK_E; ++j) {
            if (pp[j] >= 0) {
                int pos = lbase[pp[j]] + rr[j];
                pairs[pos] = ((unsigned long long)(unsigned)dd[j] << 32)
                           | (unsigned)ss[j];
            }
        }
        __syncthreads();   // lcount reset next iteration
    }
}

// ---------- fill2: per-partition scatter from its own bucket (L2-contained) ----------
__global__ __launch_bounds__(256) void fill2_kernel(
    const unsigned long long* __restrict__ pairs, const int* __restrict__ offs,
    int* __restrict__ cursor, unsigned short* __restrict__ csr_src, int ngene)
{
    int part = blockIdx.x & (NPART - 1);
    int slice = blockIdx.x >> 3;
    int nsl = gridDim.x >> 3;
    int b0 = offs[(int)((long long)part * ngene / NPART)];
    int b1 = offs[(int)((long long)(part + 1) * ngene / NPART)];
    int n = b1 - b0;
    int e0 = b0 + (int)((long long)slice * n / nsl);
    int e1 = b0 + (int)((long long)(slice + 1) * n / nsl);
    for (int i = e0 + threadIdx.x; i < e1; i += 256) {
        unsigned long long pr = pairs[i];
        int d = (int)(pr >> 32);
        unsigned short s = (unsigned short)(pr & 0xffffu);
        int pos = atomicAdd(&cursor[d], 1);
        csr_src[pos] = s;
    }
}

// ---------- conversions ----------
__global__ __launch_bounds__(256) void cvt_xd_kernel(
    const float* __restrict__ src, unsigned short* __restrict__ dst, int n8)
{
    int i = blockIdx.x * blockDim.x + threadIdx.x;
    if (i >= n8) return;
    float4 a = ((const float4*)src)[i * 2];
    float4 b = ((const float4*)src)[i * 2 + 1];
    bf16x8 v;
    v[0] = (short)f2bf(a.x); v[1] = (short)f2bf(a.y);
    v[2] = (short)f2bf(a.z); v[3] = (short)f2bf(a.w);
    v[4] = (short)f2bf(b.x); v[5] = (short)f2bf(b.y);
    v[6] = (short)f2bf(b.z); v[7] = (short)f2bf(b.w);
    ((bf16x8*)dst)[i] = v;
}

// transpose 128x128 f32 -> bf16 (WT[n][k] = W[k][n]); blockIdx picks matrix
__global__ __launch_bounds__(256) void cvt_w_kernel(
    const float* __restrict__ w0, const float* __restrict__ w1,
    const float* __restrict__ w2, const float* __restrict__ w3,
    unsigned short* __restrict__ t0, unsigned short* __restrict__ t1,
    unsigned short* __restrict__ t2, unsigned short* __restrict__ t3)
{
    const float* src = blockIdx.x == 0 ? w0 : blockIdx.x == 1 ? w1
                     : blockIdx.x == 2 ? w2 : w3;
    unsigned short* dst = blockIdx.x == 0 ? t0 : blockIdx.x == 1 ? t1
                        : blockIdx.x == 2 ? t2 : t3;
    for (int idx = threadIdx.x; idx < D * D; idx += 256) {
        int k = idx >> 7, n = idx & 127;
        dst[n * D + k] = f2bf(src[idx]);
    }
}

// ---------- gather: mean_bf16[row] = mean over neighbors of xd_bf16 ----------
__global__ __launch_bounds__(256, 6) void gather_kernel(
    const int* __restrict__ offs, const unsigned short* __restrict__ csr,
    const unsigned short* __restrict__ xdb, unsigned short* __restrict__ meanb,
    int ngene)
{
    int tid = threadIdx.x;
    int r = tid >> 4, c = tid & 15;
    int row = blockIdx.x * 16 + r;
    if (row >= ngene) return;
    int beg = offs[row], end = offs[row + 1];
    const bf16x8* tab = (const bf16x8*)xdb;
    float a0[8] = {0, 0, 0, 0, 0, 0, 0, 0};
    float a1[8] = {0, 0, 0, 0, 0, 0, 0, 0};
    int i = beg;
    for (; i + 2 <= end; i += 2) {
        int s0 = csr[i], s1 = csr[i + 1];
        bf16x8 v0 = tab[s0 * 16 + c];
        bf16x8 v1 = tab[s1 * 16 + c];
        #pragma unroll
        for (int j = 0; j < 8; ++j) {
            a0[j] += bf2f((unsigned short)v0[j]);
            a1[j] += bf2f((unsigned short)v1[j]);
        }
    }
    if (i < end) {
        int s0 = csr[i];
        bf16x8 v0 = tab[s0 * 16 + c];
        #pragma unroll
        for (int j = 0; j < 8; ++j) a0[j] += bf2f((unsigned short)v0[j]);
    }
    float inv = 1.0f / fmaxf((float)(end - beg), 1.0f);
    bf16x8 o;
    #pragma unroll
    for (int j = 0; j < 8; ++j) o[j] = (short)f2bf((a0[j] + a1[j]) * inv);
    ((bf16x8*)meanb)[row * 16 + c] = o;
}

// ---------- fused h+z MFMA kernel: 64-row LDS-staged supertile ----------
// 512 thr = 8 waves; wave w owns output cols [16w,16w+16).
// Swapped-operand MFMA: D = mfma(Wfrag, Afrag) accumulates h^T / z^T.
__global__ __launch_bounds__(512, 4) void hz_kernel(
    const unsigned short* __restrict__ meanb, const float* __restrict__ xg,
    const float* __restrict__ eps,
    const unsigned short* __restrict__ WlT, const unsigned short* __restrict__ WrT,
    const unsigned short* __restrict__ muT, const unsigned short* __restrict__ lvT,
    const float* __restrict__ bl, const float* __restrict__ mub,
    const float* __restrict__ lvb, float* __restrict__ z, int ngene, int nst)
{
    __shared__ unsigned short mean_s[ST][132];  // +4 pad
    __shared__ unsigned short xg_s[ST][132];
    __shared__ unsigned short h_s[ST][132];

    int tid = threadIdx.x;
    int wave = tid >> 6;
    int lane = tid & 63;
    int lr = lane & 15;
    int lg = lane >> 4;
    int cb = wave * 16;
    int nb = cb + lg * 4;          // this lane's 4 consecutive output cols

    float4 bl4 = *(const float4*)&bl[nb];
    float4 mb4 = *(const float4*)&mub[nb];
    float4 lb4 = *(const float4*)&lvb[nb];

    for (int st = blockIdx.x; st < nst; st += gridDim.x) {
        int rowbase = st * ST;

        // ---- stage: mean (bf16 copy) + xg (f32 -> bf16 once) ----
        for (int i = tid; i < ST * 16; i += 512) {
            int row = i >> 4, c = i & 15;
            int grow = rowbase + row;
            if (grow >= ngene) grow = ngene - 1;
            *(bf16x8*)&mean_s[row][c * 8] =
                *(const bf16x8*)&meanb[(size_t)grow * D + c * 8];
            const float* xp = &xg[(size_t)grow * D + c * 8];
            float4 x0 = *(const float4*)xp;
            float4 x1 = *(const float4*)(xp + 4);
            bf16x8 v;
            v[0] = (short)f2bf(x0.x); v[1] = (short)f2bf(x0.y);
            v[2] = (short)f2bf(x0.z); v[3] = (short)f2bf(x0.w);
            v[4] = (short)f2bf(x1.x); v[5] = (short)f2bf(x1.y);
            v[6] = (short)f2bf(x1.z); v[7] = (short)f2bf(x1.w);
            *(bf16x8*)&xg_s[row][c * 8] = v;
        }
        __syncthreads();

        // ---- h phase ----
        {
            bf16x8 wl[4], wr[4];
            #pragma unroll
            for (int kc = 0; kc < 4; ++kc) {
                int koff = kc * 32 + lg * 8;
                wl[kc] = *(const bf16x8*)&WlT[(cb + lr) * D + koff];
                wr[kc] = *(const bf16x8*)&WrT[(cb + lr) * D + koff];
            }
            #pragma unroll
            for (int rt = 0; rt < 4; ++rt) {
                int r0 = rt * 16 + lr;
                f32x4 accm = {bl4.x, bl4.y, bl4.z, bl4.w};
                f32x4 accx = {0.f, 0.f, 0.f, 0.f};
                #pragma unroll
                for (int kc = 0; kc < 4; ++kc) {
                    int koff = kc * 32 + lg * 8;
                    bf16x8 am = *(const bf16x8*)&mean_s[r0][koff];
                    bf16x8 ax = *(const bf16x8*)&xg_s[r0][koff];
                    accm = __builtin_amdgcn_mfma_f32_16x16x32_bf16(wl[kc], am, accm, 0, 0, 0);
                    accx = __builtin_amdgcn_mfma_f32_16x16x32_bf16(wr[kc], ax, accx, 0, 0, 0);
                }
                bf16x4 hp;
                #pragma unroll
                for (int r = 0; r < 4; ++r) hp[r] = (short)f2bf(accm[r] + accx[r]);
                *(bf16x4*)&h_s[r0][nb] = hp;
            }
        }
        __syncthreads();

        // ---- z phase ----
        {
            bf16x8 mu[4], lv[4];
            #pragma unroll
            for (int kc = 0; kc < 4; ++kc) {
                int koff = kc * 32 + lg * 8;
                mu[kc] = *(const bf16x8*)&muT[(cb + lr) * D + koff];
                lv[kc] = *(const bf16x8*)&lvT[(cb + lr) * D + koff];
            }
            #pragma unroll
            for (int rt = 0; rt < 4; ++rt) {
                int r0 = rt * 16 + lr;
                f32x4 zm = {mb4.x, mb4.y, mb4.z, mb4.w};
                f32x4 zl = {lb4.x, lb4.y, lb4.z, lb4.w};
                #pragma unroll
                for (int kc = 0; kc < 4; ++kc) {
                    int koff = kc * 32 + lg * 8;
                    bf16x8 ah = *(const bf16x8*)&h_s[r0][koff];
                    zm = __builtin_amdgcn_mfma_f32_16x16x32_bf16(mu[kc], ah, zm, 0, 0, 0);
                    zl = __builtin_amdgcn_mfma_f32_16x16x32_bf16(lv[kc], ah, zl, 0, 0, 0);
                }
                int orow = rowbase + r0;
                if (orow < ngene) {
                    float4 ev = *(const float4*)&eps[(size_t)orow * D + nb];
                    float4 zo;
                    zo.x = zm[0] + ev.x * __expf(zl[0]);
                    zo.y = zm[1] + ev.y * __expf(zl[1]);
                    zo.z = zm[2] + ev.z * __expf(zl[2]);
                    zo.w = zm[3] + ev.w * __expf(zl[3]);
                    *(float4*)&z[(size_t)orow * D + nb] = zo;
                }
            }
        }
        __syncthreads();
    }
}

extern "C" void kernel_launch(void* const* d_in, const int* in_sizes, int n_in,
                              void* d_out, int out_size, void* d_ws, size_t ws_size,
                              hipStream_t stream)
{
    const float* xd  = (const float*)d_in[0];
    const float* xg  = (const float*)d_in[1];
    const int* esrc  = (const int*)d_in[2];
    const int* edst  = (const int*)d_in[3];
    const float* eps = (const float*)d_in[4];
    const float* Wl  = (const float*)d_in[5];
    const float* bl  = (const float*)d_in[6];
    const float* Wr  = (const float*)d_in[7];
    const float* muW = (const float*)d_in[8];
    const float* mub = (const float*)d_in[9];
    const float* lvW = (const float*)d_in[10];
    const float* lvb = (const float*)d_in[11];

    int E = in_sizes[2];
    int ndis = in_sizes[0] / D;      // 20000
    int ngene = in_sizes[1] / D;     // 100000
    int nchunks = (ngene + CHUNK - 1) / CHUNK;   // 98 (<=128)

    // ---- ws layout ----
    char* p = (char*)d_ws;
    int* deg      = (int*)p;  p += (size_t)ngene * 4;
    int* offs     = (int*)p;  p += (size_t)(ngene + 1) * 4;
    int* cursor   = (int*)p;  p += (size_t)ngene * 4;
    int* chunksum = (int*)p;  p += 128 * 4;
    int* bcur     = (int*)p;  p += 16 * 4;
    p = (char*)(((size_t)p + 255) & ~(size_t)255);
    unsigned short* xdb   = (unsigned short*)p;  p += (size_t)ndis * D * 2;
    unsigned short* WlT   = (unsigned short*)p;  p += D * D * 2;
    unsigned short* WrT   = (unsigned short*)p;  p += D * D * 2;
    unsigned short* muT   = (unsigned short*)p;  p += D * D * 2;
    unsigned short* lvT   = (unsigned short*)p;  p += D * D * 2;
    p = (char*)(((size_t)p + 255) & ~(size_t)255);
    unsigned short* meanb = (unsigned short*)p;  p += (size_t)ngene * D * 2;
    unsigned short* csr_src = (unsigned short*)p;  // E ushorts
    // pairs (E x 8B) aliases meanb: consumed by fill2 BEFORE gather writes meanb
    unsigned long long* pairs = (unsigned long long*)meanb;

    hipMemsetAsync(deg, 0, (size_t)ngene * sizeof(int), stream);

    hist_kernel<<<2048, 256, 0, stream>>>(edst, deg, E);
    chunksum_kernel<<<nchunks, 256, 0, stream>>>(deg, chunksum, ngene);
    scanchunks_kernel<<<1, 128, 0, stream>>>(chunksum, offs, nchunks, ngene, E);
    offsets_kernel<<<nchunks, 256, 0, stream>>>(deg, chunksum, offs, cursor, ngene);
    init_bcur_kernel<<<1, NPART, 0, stream>>>(offs, bcur, ngene);

    bucket_kernel<<<1024, 256, 0, stream>>>(esrc, edst, bcur, pairs, E, ngene);
    fill2_kernel<<<2048, 256, 0, stream>>>(pairs, offs, cursor, csr_src, ngene);

    int n8 = ndis * D / 8;
    cvt_xd_kernel<<<(n8 + 255) / 256, 256, 0, stream>>>(xd, xdb, n8);
    cvt_w_kernel<<<4, 256, 0, stream>>>(Wl, Wr, muW, lvW, WlT, WrT, muT, lvT);

    gather_kernel<<<(ngene + 15) / 16, 256, 0, stream>>>(offs, csr_src, xdb, meanb, ngene);

    int nst = (ngene + ST - 1) / ST;   // 1563
    hz_kernel<<<512, 512, 0, stream>>>(meanb, xg, eps, WlT, WrT, muT, lvT,
                                       bl, mub, lvb, (float*)d_out, ngene, nst);
}

// Round 8
// 243.501 us; speedup vs baseline: 1.2856x; 1.2856x over previous
//
#include <hip/hip_runtime.h>
#include <math.h>

#define D 128
#define CHUNK 1024
#define ST 64       // hz supertile rows
#define GBIN 256    // genes per radix bin
#define CAP 6144    // staged edges per bin (mean 5120, +14 sigma)
#define BK2_E 16    // edges/thread per bucket2 batch

typedef short bf16x8 __attribute__((ext_vector_type(8)));
typedef short bf16x4 __attribute__((ext_vector_type(4)));
typedef float f32x4 __attribute__((ext_vector_type(4)));

__device__ inline unsigned short f2bf(float f) {
    union { float f; unsigned u; } v; v.f = f;
    unsigned r = v.u + 0x7fff + ((v.u >> 16) & 1);   // RNE
    return (unsigned short)(r >> 16);
}
__device__ inline float bf2f(unsigned short u) {
    union { unsigned u; float f; } v; v.u = ((unsigned)u) << 16;
    return v.f;
}

// ---------- CSR build ----------
__global__ __launch_bounds__(256) void hist_kernel(
    const int* __restrict__ edst, int* __restrict__ deg, int E)
{
    for (int e = blockIdx.x * blockDim.x + threadIdx.x; e < E;
         e += gridDim.x * blockDim.x)
        atomicAdd(&deg[edst[e]], 1);
}

__global__ __launch_bounds__(256) void chunksum_kernel(
    const int* __restrict__ deg, int* __restrict__ chunksum, int n)
{
    __shared__ int sc[256];
    int base = blockIdx.x * CHUNK;
    int t = threadIdx.x;
    int s = 0;
    for (int i = t; i < CHUNK; i += 256) {
        int idx = base + i;
        if (idx < n) s += deg[idx];
    }
    sc[t] = s;
    __syncthreads();
    for (int off = 128; off > 0; off >>= 1) {
        if (t < off) sc[t] += sc[t + off];
        __syncthreads();
    }
    if (t == 0) chunksum[blockIdx.x] = sc[0];
}

__global__ __launch_bounds__(128) void scanchunks_kernel(
    int* __restrict__ chunksum, int* __restrict__ offs, int nchunks, int n, int E)
{
    __shared__ int sc[128];
    int t = threadIdx.x;
    int v = (t < nchunks) ? chunksum[t] : 0;
    sc[t] = v;
    __syncthreads();
    for (int off = 1; off < 128; off <<= 1) {
        int add = (t >= off) ? sc[t - off] : 0;
        __syncthreads();
        sc[t] += add;
        __syncthreads();
    }
    if (t < nchunks) chunksum[t] = sc[t] - v;   // exclusive
    if (t == 0) offs[n] = E;
}

__global__ __launch_bounds__(256) void offsets_kernel(
    const int* __restrict__ deg, const int* __restrict__ chunksum,
    int* __restrict__ offs, int n)
{
    __shared__ int sc[256];
    int base = blockIdx.x * CHUNK;
    int t = threadIdx.x;
    int idx0 = base + t * 4;
    int d0 = 0, d1 = 0, d2 = 0, d3 = 0;
    if (idx0 + 0 < n) d0 = deg[idx0 + 0];
    if (idx0 + 1 < n) d1 = deg[idx0 + 1];
    if (idx0 + 2 < n) d2 = deg[idx0 + 2];
    if (idx0 + 3 < n) d3 = deg[idx0 + 3];
    int mysum = d0 + d1 + d2 + d3;
    sc[t] = mysum;
    __syncthreads();
    for (int off = 1; off < 256; off <<= 1) {
        int add = (t >= off) ? sc[t - off] : 0;
        __syncthreads();
        sc[t] += add;
        __syncthreads();
    }
    int prefix = chunksum[blockIdx.x] + sc[t] - mysum;
    if (idx0 + 0 < n) { offs[idx0 + 0] = prefix; prefix += d0; }
    if (idx0 + 1 < n) { offs[idx0 + 1] = prefix; prefix += d1; }
    if (idx0 + 2 < n) { offs[idx0 + 2] = prefix; prefix += d2; }
    if (idx0 + 3 < n) { offs[idx0 + 3] = prefix; prefix += d3; }
}

__global__ void init_bcur_kernel(const int* __restrict__ offs,
                                 int* __restrict__ bcur, int nbin)
{
    int b = blockIdx.x * blockDim.x + threadIdx.x;
    if (b < nbin) bcur[b] = offs[b * GBIN];
}

// ---------- bucket2: bin edges by dst>>8, pack (dstloc<<16|src) as uint, dense runs ----
__global__ __launch_bounds__(256) void bucket2_kernel(
    const int* __restrict__ esrc, const int* __restrict__ edst,
    int* __restrict__ bcur, unsigned* __restrict__ pairs2, int E, int nbin)
{
    __shared__ int lcount[512];
    __shared__ int lbase[512];
    int t = threadIdx.x;
    const int batch = 256 * BK2_E;   // 4096 edges per block-iteration
    for (long long base = (long long)blockIdx.x * batch; base < E;
         base += (long long)gridDim.x * batch) {
        for (int b = t; b < nbin; b += 256) lcount[b] = 0;
        __syncthreads();
        int bb[BK2_E], rr[BK2_E];
        unsigned pv[BK2_E];
        #pragma unroll
        for (int j = 0; j < BK2_E; ++j) {
            int e = (int)base + t + j * 256;   // coalesced per sub-batch
            bb[j] = -1;
            if (e < E) {
                int dd = __builtin_nontemporal_load(&edst[e]);
                int ss = __builtin_nontemporal_load(&esrc[e]);
                int bin = dd >> 8;             // GBIN = 256
                bb[j] = bin;
                pv[j] = ((unsigned)(dd & (GBIN - 1)) << 16) | (unsigned)ss;
                rr[j] = atomicAdd(&lcount[bin], 1);
            }
        }
        __syncthreads();
        for (int b = t; b < nbin; b += 256)
            lbase[b] = lcount[b] ? atomicAdd(&bcur[b], lcount[b]) : 0;
        __syncthreads();
        #pragma unroll
        for (int j = 0; j < BK2_E; ++j)
            if (bb[j] >= 0) pairs2[lbase[bb[j]] + rr[j]] = pv[j];
        __syncthreads();   // lcount reset next iteration
    }
}

// ---------- fill3: per-bin LDS scatter -> dense csr segment write ----------
__global__ __launch_bounds__(256) void fill3_kernel(
    const unsigned* __restrict__ pairs2, const int* __restrict__ offs,
    unsigned short* __restrict__ csr, int ngene)
{
    __shared__ int lcur[GBIN];
    __shared__ unsigned short stage[CAP];
    int b = blockIdx.x;
    int g0 = b * GBIN;
    int g1 = min(g0 + GBIN, ngene);
    int ng = g1 - g0;
    int sb = offs[g0], se = offs[g1];
    int n = se - sb;
    for (int g = threadIdx.x; g < ng; g += 256)
        lcur[g] = offs[g0 + g] - sb;
    __syncthreads();
    if (n <= CAP) {
        for (int i = sb + threadIdx.x; i < se; i += 256) {
            unsigned u = pairs2[i];
            int dl = u >> 16;
            int pos = atomicAdd(&lcur[dl], 1);
            stage[pos] = (unsigned short)(u & 0xffffu);
        }
        __syncthreads();
        for (int i = threadIdx.x; i < n; i += 256)
            csr[sb + i] = stage[i];
    } else {   // overflow fallback: correctness-preserving global scatter
        for (int i = sb + threadIdx.x; i < se; i += 256) {
            unsigned u = pairs2[i];
            int dl = u >> 16;
            int pos = atomicAdd(&lcur[dl], 1);
            csr[sb + pos] = (unsigned short)(u & 0xffffu);
        }
    }
}

// ---------- conversions ----------
__global__ __launch_bounds__(256) void cvt_xd_kernel(
    const float* __restrict__ src, unsigned short* __restrict__ dst, int n8)
{
    int i = blockIdx.x * blockDim.x + threadIdx.x;
    if (i >= n8) return;
    float4 a = ((const float4*)src)[i * 2];
    float4 b = ((const float4*)src)[i * 2 + 1];
    bf16x8 v;
    v[0] = (short)f2bf(a.x); v[1] = (short)f2bf(a.y);
    v[2] = (short)f2bf(a.z); v[3] = (short)f2bf(a.w);
    v[4] = (short)f2bf(b.x); v[5] = (short)f2bf(b.y);
    v[6] = (short)f2bf(b.z); v[7] = (short)f2bf(b.w);
    ((bf16x8*)dst)[i] = v;
}

// transpose 128x128 f32 -> bf16 (WT[n][k] = W[k][n]); blockIdx picks matrix
__global__ __launch_bounds__(256) void cvt_w_kernel(
    const float* __restrict__ w0, const float* __restrict__ w1,
    const float* __restrict__ w2, const float* __restrict__ w3,
    unsigned short* __restrict__ t0, unsigned short* __restrict__ t1,
    unsigned short* __restrict__ t2, unsigned short* __restrict__ t3)
{
    const float* src = blockIdx.x == 0 ? w0 : blockIdx.x == 1 ? w1
                     : blockIdx.x == 2 ? w2 : w3;
    unsigned short* dst = blockIdx.x == 0 ? t0 : blockIdx.x == 1 ? t1
                        : blockIdx.x == 2 ? t2 : t3;
    for (int idx = threadIdx.x; idx < D * D; idx += 256) {
        int k = idx >> 7, n = idx & 127;
        dst[n * D + k] = f2bf(src[idx]);
    }
}

// ---------- gather: mean_bf16[row] = mean over neighbors of xd_bf16 ----------
__global__ __launch_bounds__(256, 6) void gather_kernel(
    const int* __restrict__ offs, const unsigned short* __restrict__ csr,
    const unsigned short* __restrict__ xdb, unsigned short* __restrict__ meanb,
    int ngene)
{
    int tid = threadIdx.x;
    int r = tid >> 4, c = tid & 15;
    int row = blockIdx.x * 16 + r;
    if (row >= ngene) return;
    int beg = offs[row], end = offs[row + 1];
    const bf16x8* tab = (const bf16x8*)xdb;
    float a0[8] = {0, 0, 0, 0, 0, 0, 0, 0};
    float a1[8] = {0, 0, 0, 0, 0, 0, 0, 0};
    int i = beg;
    for (; i + 2 <= end; i += 2) {
        int s0 = csr[i], s1 = csr[i + 1];
        bf16x8 v0 = tab[s0 * 16 + c];
        bf16x8 v1 = tab[s1 * 16 + c];
        #pragma unroll
        for (int j = 0; j < 8; ++j) {
            a0[j] += bf2f((unsigned short)v0[j]);
            a1[j] += bf2f((unsigned short)v1[j]);
        }
    }
    if (i < end) {
        int s0 = csr[i];
        bf16x8 v0 = tab[s0 * 16 + c];
        #pragma unroll
        for (int j = 0; j < 8; ++j) a0[j] += bf2f((unsigned short)v0[j]);
    }
    float inv = 1.0f / fmaxf((float)(end - beg), 1.0f);
    bf16x8 o;
    #pragma unroll
    for (int j = 0; j < 8; ++j) o[j] = (short)f2bf((a0[j] + a1[j]) * inv);
    ((bf16x8*)meanb)[row * 16 + c] = o;
}

// ---------- fused h+z MFMA kernel: 64-row LDS-staged supertile ----------
// 512 thr = 8 waves; wave w owns output cols [16w,16w+16).
// Swapped-operand MFMA: D = mfma(Wfrag, Afrag) accumulates h^T / z^T.
__global__ __launch_bounds__(512, 4) void hz_kernel(
    const unsigned short* __restrict__ meanb, const float* __restrict__ xg,
    const float* __restrict__ eps,
    const unsigned short* __restrict__ WlT, const unsigned short* __restrict__ WrT,
    const unsigned short* __restrict__ muT, const unsigned short* __restrict__ lvT,
    const float* __restrict__ bl, const float* __restrict__ mub,
    const float* __restrict__ lvb, float* __restrict__ z, int ngene, int nst)
{
    __shared__ unsigned short mean_s[ST][132];  // +4 pad
    __shared__ unsigned short xg_s[ST][132];
    __shared__ unsigned short h_s[ST][132];

    int tid = threadIdx.x;
    int wave = tid >> 6;
    int lane = tid & 63;
    int lr = lane & 15;
    int lg = lane >> 4;
    int cb = wave * 16;
    int nb = cb + lg * 4;          // this lane's 4 consecutive output cols

    float4 bl4 = *(const float4*)&bl[nb];
    float4 mb4 = *(const float4*)&mub[nb];
    float4 lb4 = *(const float4*)&lvb[nb];

    for (int st = blockIdx.x; st < nst; st += gridDim.x) {
        int rowbase = st * ST;

        // ---- stage: mean (bf16 copy) + xg (f32 -> bf16 once) ----
        for (int i = tid; i < ST * 16; i += 512) {
            int row = i >> 4, c = i & 15;
            int grow = rowbase + row;
            if (grow >= ngene) grow = ngene - 1;
            *(bf16x8*)&mean_s[row][c * 8] =
                *(const bf16x8*)&meanb[(size_t)grow * D + c * 8];
            const float* xp = &xg[(size_t)grow * D + c * 8];
            float4 x0 = *(const float4*)xp;
            float4 x1 = *(const float4*)(xp + 4);
            bf16x8 v;
            v[0] = (short)f2bf(x0.x); v[1] = (short)f2bf(x0.y);
            v[2] = (short)f2bf(x0.z); v[3] = (short)f2bf(x0.w);
            v[4] = (short)f2bf(x1.x); v[5] = (short)f2bf(x1.y);
            v[6] = (short)f2bf(x1.z); v[7] = (short)f2bf(x1.w);
            *(bf16x8*)&xg_s[row][c * 8] = v;
        }
        __syncthreads();

        // ---- h phase ----
        {
            bf16x8 wl[4], wr[4];
            #pragma unroll
            for (int kc = 0; kc < 4; ++kc) {
                int koff = kc * 32 + lg * 8;
                wl[kc] = *(const bf16x8*)&WlT[(cb + lr) * D + koff];
                wr[kc] = *(const bf16x8*)&WrT[(cb + lr) * D + koff];
            }
            #pragma unroll
            for (int rt = 0; rt < 4; ++rt) {
                int r0 = rt * 16 + lr;
                f32x4 accm = {bl4.x, bl4.y, bl4.z, bl4.w};
                f32x4 accx = {0.f, 0.f, 0.f, 0.f};
                #pragma unroll
                for (int kc = 0; kc < 4; ++kc) {
                    int koff = kc * 32 + lg * 8;
                    bf16x8 am = *(const bf16x8*)&mean_s[r0][koff];
                    bf16x8 ax = *(const bf16x8*)&xg_s[r0][koff];
                    accm = __builtin_amdgcn_mfma_f32_16x16x32_bf16(wl[kc], am, accm, 0, 0, 0);
                    accx = __builtin_amdgcn_mfma_f32_16x16x32_bf16(wr[kc], ax, accx, 0, 0, 0);
                }
                bf16x4 hp;
                #pragma unroll
                for (int r = 0; r < 4; ++r) hp[r] = (short)f2bf(accm[r] + accx[r]);
                *(bf16x4*)&h_s[r0][nb] = hp;
            }
        }
        __syncthreads();

        // ---- z phase ----
        {
            bf16x8 mu[4], lv[4];
            #pragma unroll
            for (int kc = 0; kc < 4; ++kc) {
                int koff = kc * 32 + lg * 8;
                mu[kc] = *(const bf16x8*)&muT[(cb + lr) * D + koff];
                lv[kc] = *(const bf16x8*)&lvT[(cb + lr) * D + koff];
            }
            #pragma unroll
            for (int rt = 0; rt < 4; ++rt) {
                int r0 = rt * 16 + lr;
                f32x4 zm = {mb4.x, mb4.y, mb4.z, mb4.w};
                f32x4 zl = {lb4.x, lb4.y, lb4.z, lb4.w};
                #pragma unroll
                for (int kc = 0; kc < 4; ++kc) {
                    int koff = kc * 32 + lg * 8;
                    bf16x8 ah = *(const bf16x8*)&h_s[r0][koff];
                    zm = __builtin_amdgcn_mfma_f32_16x16x32_bf16(mu[kc], ah, zm, 0, 0, 0);
                    zl = __builtin_amdgcn_mfma_f32_16x16x32_bf16(lv[kc], ah, zl, 0, 0, 0);
                }
                int orow = rowbase + r0;
                if (orow < ngene) {
                    float4 ev = *(const float4*)&eps[(size_t)orow * D + nb];
                    float4 zo;
                    zo.x = zm[0] + ev.x * __expf(zl[0]);
                    zo.y = zm[1] + ev.y * __expf(zl[1]);
                    zo.z = zm[2] + ev.z * __expf(zl[2]);
                    zo.w = zm[3] + ev.w * __expf(zl[3]);
                    *(float4*)&z[(size_t)orow * D + nb] = zo;
                }
            }
        }
        __syncthreads();
    }
}

extern "C" void kernel_launch(void* const* d_in, const int* in_sizes, int n_in,
                              void* d_out, int out_size, void* d_ws, size_t ws_size,
                              hipStream_t stream)
{
    const float* xd  = (const float*)d_in[0];
    const float* xg  = (const float*)d_in[1];
    const int* esrc  = (const int*)d_in[2];
    const int* edst  = (const int*)d_in[3];
    const float* eps = (const float*)d_in[4];
    const float* Wl  = (const float*)d_in[5];
    const float* bl  = (const float*)d_in[6];
    const float* Wr  = (const float*)d_in[7];
    const float* muW = (const float*)d_in[8];
    const float* mub = (const float*)d_in[9];
    const float* lvW = (const float*)d_in[10];
    const float* lvb = (const float*)d_in[11];

    int E = in_sizes[2];
    int ndis = in_sizes[0] / D;      // 20000
    int ngene = in_sizes[1] / D;     // 100000
    int nchunks = (ngene + CHUNK - 1) / CHUNK;   // 98 (<=128)
    int nbin = (ngene + GBIN - 1) / GBIN;        // 391

    // ---- ws layout ----
    char* p = (char*)d_ws;
    int* deg      = (int*)p;  p += (size_t)ngene * 4;
    int* offs     = (int*)p;  p += (size_t)(ngene + 1) * 4;
    int* chunksum = (int*)p;  p += 128 * 4;
    int* bcur     = (int*)p;  p += 512 * 4;
    p = (char*)(((size_t)p + 255) & ~(size_t)255);
    unsigned short* xdb   = (unsigned short*)p;  p += (size_t)ndis * D * 2;
    unsigned short* WlT   = (unsigned short*)p;  p += D * D * 2;
    unsigned short* WrT   = (unsigned short*)p;  p += D * D * 2;
    unsigned short* muT   = (unsigned short*)p;  p += D * D * 2;
    unsigned short* lvT   = (unsigned short*)p;  p += D * D * 2;
    p = (char*)(((size_t)p + 255) & ~(size_t)255);
    unsigned short* meanb = (unsigned short*)p;  p += (size_t)ngene * D * 2;
    unsigned short* csr_src = (unsigned short*)p;  // E ushorts
    // pairs2 (E x 4B) aliases meanb: consumed by fill3 BEFORE gather writes meanb
    unsigned* pairs2 = (unsigned*)meanb;

    hipMemsetAsync(deg, 0, (size_t)ngene * sizeof(int), stream);

    hist_kernel<<<2048, 256, 0, stream>>>(edst, deg, E);
    chunksum_kernel<<<nchunks, 256, 0, stream>>>(deg, chunksum, ngene);
    scanchunks_kernel<<<1, 128, 0, stream>>>(chunksum, offs, nchunks, ngene, E);
    offsets_kernel<<<nchunks, 256, 0, stream>>>(deg, chunksum, offs, ngene);
    init_bcur_kernel<<<(nbin + 255) / 256, 256, 0, stream>>>(offs, bcur, nbin);

    bucket2_kernel<<<512, 256, 0, stream>>>(esrc, edst, bcur, pairs2, E, nbin);
    fill3_kernel<<<nbin, 256, 0, stream>>>(pairs2, offs, csr_src, ngene);

    int n8 = ndis * D / 8;
    cvt_xd_kernel<<<(n8 + 255) / 256, 256, 0, stream>>>(xd, xdb, n8);
    cvt_w_kernel<<<4, 256, 0, stream>>>(Wl, Wr, muW, lvW, WlT, WrT, muT, lvT);

    gather_kernel<<<(ngene + 15) / 16, 256, 0, stream>>>(offs, csr_src, xdb, meanb, ngene);

    int nst = (ngene + ST - 1) / ST;   // 1563
    hz_kernel<<<512, 512, 0, stream>>>(meanb, xg, eps, WlT, WrT, muT, lvT,
                                       bl, mub, lvb, (float*)d_out, ngene, nst);
}

// Round 9
// 193.822 us; speedup vs baseline: 1.6152x; 1.2563x over previous
//
#include <hip/hip_runtime.h>
#include <math.h>

#define D 128
#define ST 64       // hz supertile rows
#define GBIN 256    // genes per radix bin
#define CAP 6144    // staged edges per bin (mean 5120)
#define BK2_E 16    // edges/thread per bucket2 batch
#define NBMAX 512

typedef short bf16x8 __attribute__((ext_vector_type(8)));
typedef short bf16x4 __attribute__((ext_vector_type(4)));
typedef float f32x4 __attribute__((ext_vector_type(4)));

__device__ inline unsigned short f2bf(float f) {
    union { float f; unsigned u; } v; v.f = f;
    unsigned r = v.u + 0x7fff + ((v.u >> 16) & 1);   // RNE
    return (unsigned short)(r >> 16);
}
__device__ inline float bf2f(unsigned short u) {
    union { unsigned u; float f; } v; v.u = ((unsigned)u) << 16;
    return v.f;
}

// ---------- binhist: LDS histogram over coarse bins (dst>>8), flush per block ----------
__global__ __launch_bounds__(256) void binhist_kernel(
    const int* __restrict__ edst, int* __restrict__ bincnt, int E, int nbin)
{
    __shared__ int lh[NBMAX];
    int t = threadIdx.x;
    for (int b = t; b < nbin; b += 256) lh[b] = 0;
    __syncthreads();
    for (long long e = (long long)blockIdx.x * blockDim.x + t; e < E;
         e += (long long)gridDim.x * blockDim.x) {
        int d = __builtin_nontemporal_load(&edst[(int)e]);
        atomicAdd(&lh[d >> 8], 1);
    }
    __syncthreads();
    for (int b = t; b < nbin; b += 256)
        if (lh[b]) atomicAdd(&bincnt[b], lh[b]);
}

// ---------- scanbins: exclusive scan of bin counts; seed bcur; offs[n]=E ----------
__global__ __launch_bounds__(NBMAX) void scanbins_kernel(
    const int* __restrict__ bincnt, int* __restrict__ binbase,
    int* __restrict__ bcur, int* __restrict__ offs, int nbin, int ngene, int E)
{
    __shared__ int sc[NBMAX];
    int t = threadIdx.x;
    int v = (t < nbin) ? bincnt[t] : 0;
    sc[t] = v;
    __syncthreads();
    for (int off = 1; off < NBMAX; off <<= 1) {
        int add = (t >= off) ? sc[t - off] : 0;
        __syncthreads();
        sc[t] += add;
        __syncthreads();
    }
    if (t < nbin) {
        int base = sc[t] - v;   // exclusive
        binbase[t] = base;
        bcur[t] = base;
    }
    if (t == 0) { binbase[nbin] = E; offs[ngene] = E; }
}

// ---------- bucket2: bin edges by dst>>8, pack (dstloc<<16|src) as uint, dense runs ----
__global__ __launch_bounds__(256) void bucket2_kernel(
    const int* __restrict__ esrc, const int* __restrict__ edst,
    int* __restrict__ bcur, unsigned* __restrict__ pairs2, int E, int nbin)
{
    __shared__ int lcount[NBMAX];
    __shared__ int lbase[NBMAX];
    int t = threadIdx.x;
    const int batch = 256 * BK2_E;   // 4096 edges per block-iteration
    for (long long base = (long long)blockIdx.x * batch; base < E;
         base += (long long)gridDim.x * batch) {
        for (int b = t; b < nbin; b += 256) lcount[b] = 0;
        __syncthreads();
        int bb[BK2_E], rr[BK2_E];
        unsigned pv[BK2_E];
        #pragma unroll
        for (int j = 0; j < BK2_E; ++j) {
            int e = (int)base + t + j * 256;   // coalesced per sub-batch
            bb[j] = -1;
            if (e < E) {
                int dd = __builtin_nontemporal_load(&edst[e]);
                int ss = __builtin_nontemporal_load(&esrc[e]);
                int bin = dd >> 8;             // GBIN = 256
                bb[j] = bin;
                pv[j] = ((unsigned)(dd & (GBIN - 1)) << 16) | (unsigned)ss;
                rr[j] = atomicAdd(&lcount[bin], 1);
            }
        }
        __syncthreads();
        for (int b = t; b < nbin; b += 256)
            lbase[b] = lcount[b] ? atomicAdd(&bcur[b], lcount[b]) : 0;
        __syncthreads();
        #pragma unroll
        for (int j = 0; j < BK2_E; ++j)
            if (bb[j] >= 0) pairs2[lbase[bb[j]] + rr[j]] = pv[j];
        __syncthreads();   // lcount reset next iteration
    }
}

// ---------- fill3b: per-bin gene-histogram + scan -> offs (dense) + LDS scatter -> csr ----
__global__ __launch_bounds__(256) void fill3b_kernel(
    const unsigned* __restrict__ pairs2, const int* __restrict__ binbase,
    int* __restrict__ offs, unsigned short* __restrict__ csr, int ngene)
{
    __shared__ int lhist[GBIN];
    __shared__ int lofs[GBIN];
    __shared__ int lcur[GBIN];
    __shared__ unsigned short stage[CAP];
    int b = blockIdx.x;
    int t = threadIdx.x;
    int g0 = b * GBIN;
    int ng = min(GBIN, ngene - g0);
    int sb = binbase[b], se = binbase[b + 1];
    int n = se - sb;

    lhist[t] = 0;
    __syncthreads();
    for (int i = sb + t; i < se; i += 256)
        atomicAdd(&lhist[pairs2[i] >> 16], 1);
    __syncthreads();
    // exclusive scan of lhist (256 wide, Hillis-Steele)
    int v = lhist[t];
    lofs[t] = v;
    __syncthreads();
    for (int off = 1; off < GBIN; off <<= 1) {
        int add = (t >= off) ? lofs[t - off] : 0;
        __syncthreads();
        lofs[t] += add;
        __syncthreads();
    }
    int myofs = lofs[t] - v;   // exclusive
    lcur[t] = myofs;
    if (t < ng) offs[g0 + t] = sb + myofs;   // dense 1KB run
    __syncthreads();

    if (n <= CAP) {
        for (int i = sb + t; i < se; i += 256) {
            unsigned u = pairs2[i];
            int pos = atomicAdd(&lcur[u >> 16], 1);
            stage[pos] = (unsigned short)(u & 0xffffu);
        }
        __syncthreads();
        for (int i = t; i < n; i += 256)
            csr[sb + i] = stage[i];
    } else {   // overflow fallback: correctness-preserving global scatter
        for (int i = sb + t; i < se; i += 256) {
            unsigned u = pairs2[i];
            int pos = atomicAdd(&lcur[u >> 16], 1);
            csr[sb + pos] = (unsigned short)(u & 0xffffu);
        }
    }
}

// ---------- conversions ----------
__global__ __launch_bounds__(256) void cvt_xd_kernel(
    const float* __restrict__ src, unsigned short* __restrict__ dst, int n8)
{
    int i = blockIdx.x * blockDim.x + threadIdx.x;
    if (i >= n8) return;
    float4 a = ((const float4*)src)[i * 2];
    float4 b = ((const float4*)src)[i * 2 + 1];
    bf16x8 v;
    v[0] = (short)f2bf(a.x); v[1] = (short)f2bf(a.y);
    v[2] = (short)f2bf(a.z); v[3] = (short)f2bf(a.w);
    v[4] = (short)f2bf(b.x); v[5] = (short)f2bf(b.y);
    v[6] = (short)f2bf(b.z); v[7] = (short)f2bf(b.w);
    ((bf16x8*)dst)[i] = v;
}

// transpose 128x128 f32 -> bf16 (WT[n][k] = W[k][n]); blockIdx picks matrix
__global__ __launch_bounds__(256) void cvt_w_kernel(
    const float* __restrict__ w0, const float* __restrict__ w1,
    const float* __restrict__ w2, const float* __restrict__ w3,
    unsigned short* __restrict__ t0, unsigned short* __restrict__ t1,
    unsigned short* __restrict__ t2, unsigned short* __restrict__ t3)
{
    const float* src = blockIdx.x == 0 ? w0 : blockIdx.x == 1 ? w1
                     : blockIdx.x == 2 ? w2 : w3;
    unsigned short* dst = blockIdx.x == 0 ? t0 : blockIdx.x == 1 ? t1
                        : blockIdx.x == 2 ? t2 : t3;
    for (int idx = threadIdx.x; idx < D * D; idx += 256) {
        int k = idx >> 7, n = idx & 127;
        dst[n * D + k] = f2bf(src[idx]);
    }
}

// ---------- gather: mean_bf16[row] = mean over neighbors of xd_bf16 ----------
__global__ __launch_bounds__(256, 6) void gather_kernel(
    const int* __restrict__ offs, const unsigned short* __restrict__ csr,
    const unsigned short* __restrict__ xdb, unsigned short* __restrict__ meanb,
    int ngene)
{
    int tid = threadIdx.x;
    int r = tid >> 4, c = tid & 15;
    int row = blockIdx.x * 16 + r;
    if (row >= ngene) return;
    int beg = offs[row], end = offs[row + 1];
    const bf16x8* tab = (const bf16x8*)xdb;
    float a0[8] = {0, 0, 0, 0, 0, 0, 0, 0};
    float a1[8] = {0, 0, 0, 0, 0, 0, 0, 0};
    int i = beg;
    for (; i + 2 <= end; i += 2) {
        int s0 = csr[i], s1 = csr[i + 1];
        bf16x8 v0 = tab[s0 * 16 + c];
        bf16x8 v1 = tab[s1 * 16 + c];
        #pragma unroll
        for (int j = 0; j < 8; ++j) {
            a0[j] += bf2f((unsigned short)v0[j]);
            a1[j] += bf2f((unsigned short)v1[j]);
        }
    }
    if (i < end) {
        int s0 = csr[i];
        bf16x8 v0 = tab[s0 * 16 + c];
        #pragma unroll
        for (int j = 0; j < 8; ++j) a0[j] += bf2f((unsigned short)v0[j]);
    }
    float inv = 1.0f / fmaxf((float)(end - beg), 1.0f);
    bf16x8 o;
    #pragma unroll
    for (int j = 0; j < 8; ++j) o[j] = (short)f2bf((a0[j] + a1[j]) * inv);
    ((bf16x8*)meanb)[row * 16 + c] = o;
}

// ---------- fused h+z MFMA kernel: 64-row LDS-staged supertile ----------
// 512 thr = 8 waves; wave w owns output cols [16w,16w+16).
// Swapped-operand MFMA: D = mfma(Wfrag, Afrag) accumulates h^T / z^T.
__global__ __launch_bounds__(512, 4) void hz_kernel(
    const unsigned short* __restrict__ meanb, const float* __restrict__ xg,
    const float* __restrict__ eps,
    const unsigned short* __restrict__ WlT, const unsigned short* __restrict__ WrT,
    const unsigned short* __restrict__ muT, const unsigned short* __restrict__ lvT,
    const float* __restrict__ bl, const float* __restrict__ mub,
    const float* __restrict__ lvb, float* __restrict__ z, int ngene, int nst)
{
    __shared__ unsigned short mean_s[ST][132];  // +4 pad
    __shared__ unsigned short xg_s[ST][132];
    __shared__ unsigned short h_s[ST][132];

    int tid = threadIdx.x;
    int wave = tid >> 6;
    int lane = tid & 63;
    int lr = lane & 15;
    int lg = lane >> 4;
    int cb = wave * 16;
    int nb = cb + lg * 4;          // this lane's 4 consecutive output cols

    float4 bl4 = *(const float4*)&bl[nb];
    float4 mb4 = *(const float4*)&mub[nb];
    float4 lb4 = *(const float4*)&lvb[nb];

    for (int st = blockIdx.x; st < nst; st += gridDim.x) {
        int rowbase = st * ST;

        // ---- stage: mean (bf16 copy) + xg (f32 -> bf16 once) ----
        for (int i = tid; i < ST * 16; i += 512) {
            int row = i >> 4, c = i & 15;
            int grow = rowbase + row;
            if (grow >= ngene) grow = ngene - 1;
            *(bf16x8*)&mean_s[row][c * 8] =
                *(const bf16x8*)&meanb[(size_t)grow * D + c * 8];
            const float* xp = &xg[(size_t)grow * D + c * 8];
            float4 x0 = *(const float4*)xp;
            float4 x1 = *(const float4*)(xp + 4);
            bf16x8 v;
            v[0] = (short)f2bf(x0.x); v[1] = (short)f2bf(x0.y);
            v[2] = (short)f2bf(x0.z); v[3] = (short)f2bf(x0.w);
            v[4] = (short)f2bf(x1.x); v[5] = (short)f2bf(x1.y);
            v[6] = (short)f2bf(x1.z); v[7] = (short)f2bf(x1.w);
            *(bf16x8*)&xg_s[row][c * 8] = v;
        }
        __syncthreads();

        // ---- h phase ----
        {
            bf16x8 wl[4], wr[4];
            #pragma unroll
            for (int kc = 0; kc < 4; ++kc) {
                int koff = kc * 32 + lg * 8;
                wl[kc] = *(const bf16x8*)&WlT[(cb + lr) * D + koff];
                wr[kc] = *(const bf16x8*)&WrT[(cb + lr) * D + koff];
            }
            #pragma unroll
            for (int rt = 0; rt < 4; ++rt) {
                int r0 = rt * 16 + lr;
                f32x4 accm = {bl4.x, bl4.y, bl4.z, bl4.w};
                f32x4 accx = {0.f, 0.f, 0.f, 0.f};
                #pragma unroll
                for (int kc = 0; kc < 4; ++kc) {
                    int koff = kc * 32 + lg * 8;
                    bf16x8 am = *(const bf16x8*)&mean_s[r0][koff];
                    bf16x8 ax = *(const bf16x8*)&xg_s[r0][koff];
                    accm = __builtin_amdgcn_mfma_f32_16x16x32_bf16(wl[kc], am, accm, 0, 0, 0);
                    accx = __builtin_amdgcn_mfma_f32_16x16x32_bf16(wr[kc], ax, accx, 0, 0, 0);
                }
                bf16x4 hp;
                #pragma unroll
                for (int r = 0; r < 4; ++r) hp[r] = (short)f2bf(accm[r] + accx[r]);
                *(bf16x4*)&h_s[r0][nb] = hp;
            }
        }
        __syncthreads();

        // ---- z phase ----
        {
            bf16x8 mu[4], lv[4];
            #pragma unroll
            for (int kc = 0; kc < 4; ++kc) {
                int koff = kc * 32 + lg * 8;
                mu[kc] = *(const bf16x8*)&muT[(cb + lr) * D + koff];
                lv[kc] = *(const bf16x8*)&lvT[(cb + lr) * D + koff];
            }
            #pragma unroll
            for (int rt = 0; rt < 4; ++rt) {
                int r0 = rt * 16 + lr;
                f32x4 zm = {mb4.x, mb4.y, mb4.z, mb4.w};
                f32x4 zl = {lb4.x, lb4.y, lb4.z, lb4.w};
                #pragma unroll
                for (int kc = 0; kc < 4; ++kc) {
                    int koff = kc * 32 + lg * 8;
                    bf16x8 ah = *(const bf16x8*)&h_s[r0][koff];
                    zm = __builtin_amdgcn_mfma_f32_16x16x32_bf16(mu[kc], ah, zm, 0, 0, 0);
                    zl = __builtin_amdgcn_mfma_f32_16x16x32_bf16(lv[kc], ah, zl, 0, 0, 0);
                }
                int orow = rowbase + r0;
                if (orow < ngene) {
                    float4 ev = *(const float4*)&eps[(size_t)orow * D + nb];
                    float4 zo;
                    zo.x = zm[0] + ev.x * __expf(zl[0]);
                    zo.y = zm[1] + ev.y * __expf(zl[1]);
                    zo.z = zm[2] + ev.z * __expf(zl[2]);
                    zo.w = zm[3] + ev.w * __expf(zl[3]);
                    *(float4*)&z[(size_t)orow * D + nb] = zo;
                }
            }
        }
        __syncthreads();
    }
}

extern "C" void kernel_launch(void* const* d_in, const int* in_sizes, int n_in,
                              void* d_out, int out_size, void* d_ws, size_t ws_size,
                              hipStream_t stream)
{
    const float* xd  = (const float*)d_in[0];
    const float* xg  = (const float*)d_in[1];
    const int* esrc  = (const int*)d_in[2];
    const int* edst  = (const int*)d_in[3];
    const float* eps = (const float*)d_in[4];
    const float* Wl  = (const float*)d_in[5];
    const float* bl  = (const float*)d_in[6];
    const float* Wr  = (const float*)d_in[7];
    const float* muW = (const float*)d_in[8];
    const float* mub = (const float*)d_in[9];
    const float* lvW = (const float*)d_in[10];
    const float* lvb = (const float*)d_in[11];

    int E = in_sizes[2];
    int ndis = in_sizes[0] / D;      // 20000
    int ngene = in_sizes[1] / D;     // 100000
    int nbin = (ngene + GBIN - 1) / GBIN;        // 391 (<= NBMAX)

    // ---- ws layout ----
    char* p = (char*)d_ws;
    int* offs     = (int*)p;  p += (size_t)(ngene + 1) * 4;
    int* bincnt   = (int*)p;  p += NBMAX * 4;
    int* binbase  = (int*)p;  p += (NBMAX + 1) * 4;
    int* bcur     = (int*)p;  p += NBMAX * 4;
    p = (char*)(((size_t)p + 255) & ~(size_t)255);
    unsigned short* xdb   = (unsigned short*)p;  p += (size_t)ndis * D * 2;
    unsigned short* WlT   = (unsigned short*)p;  p += D * D * 2;
    unsigned short* WrT   = (unsigned short*)p;  p += D * D * 2;
    unsigned short* muT   = (unsigned short*)p;  p += D * D * 2;
    unsigned short* lvT   = (unsigned short*)p;  p += D * D * 2;
    p = (char*)(((size_t)p + 255) & ~(size_t)255);
    unsigned short* meanb = (unsigned short*)p;  p += (size_t)ngene * D * 2;
    unsigned short* csr_src = (unsigned short*)p;  // E ushorts
    // pairs2 (E x 4B) aliases meanb: consumed by fill3b BEFORE gather writes meanb
    unsigned* pairs2 = (unsigned*)meanb;

    hipMemsetAsync(bincnt, 0, NBMAX * sizeof(int), stream);

    binhist_kernel<<<1024, 256, 0, stream>>>(edst, bincnt, E, nbin);
    scanbins_kernel<<<1, NBMAX, 0, stream>>>(bincnt, binbase, bcur, offs,
                                             nbin, ngene, E);
    bucket2_kernel<<<512, 256, 0, stream>>>(esrc, edst, bcur, pairs2, E, nbin);
    fill3b_kernel<<<nbin, 256, 0, stream>>>(pairs2, binbase, offs, csr_src, ngene);

    int n8 = ndis * D / 8;
    cvt_xd_kernel<<<(n8 + 255) / 256, 256, 0, stream>>>(xd, xdb, n8);
    cvt_w_kernel<<<4, 256, 0, stream>>>(Wl, Wr, muW, lvW, WlT, WrT, muT, lvT);

    gather_kernel<<<(ngene + 15) / 16, 256, 0, stream>>>(offs, csr_src, xdb, meanb, ngene);

    int nst = (ngene + ST - 1) / ST;   // 1563
    hz_kernel<<<512, 512, 0, stream>>>(meanb, xg, eps, WlT, WrT, muT, lvT,
                                       bl, mub, lvb, (float*)d_out, ngene, nst);
}